// Round 2
// baseline (208.347 us; speedup 1.0000x reference)
//
#include <hip/hip_runtime.h>

namespace {

constexpr int IC = 32;
constexpr int OC = 64;
constexpr int N  = 64;
constexpr int LDS_STRIDE = 76;   // 76 ≡ 4 (mod 8): 4-rows-apart y-groups get +16 bank offset
                                 // (pitch 72 had 4*72 ≡ 0 mod 32 -> 4-way conflicts, 2.8e7 cyc)
constexpr int IC_CHUNK = 8;      // ic-split x4: abs is per-ic, so out = sum_ic |conv_ic| is
                                 // block-separable over ic -> 2048 blocks, atomicAdd epilogue

// out[b,oc,y,x] = sum_ic | sum_{a,q=0..6} kf[a][q] * img[(y-2+a)%64][(x-2+q)%64] |
// kf[a][q] = ker[6-a][6-q]
// LDS tile: H[yy][xx] = img[(yy-2)%64][(xx-4)%64], yy in [0,70), xx in [2,72)
__global__ __launch_bounds__(256, 7) void optconv_abs_sum(
    const float* __restrict__ img,   // [8][32][64][64]
    const float* __restrict__ ker,   // [64][32][7][7]
    float* __restrict__ out)         // [8][64][64][64] (pre-zeroed)
{
    __shared__ float H[70 * LDS_STRIDE];

    const int bid   = blockIdx.x;
    const int oc    = bid & 63;          // innermost: 64 consecutive blocks share img planes
    const int chunk = (bid >> 6) & 3;
    const int b     = bid >> 8;
    const int tid   = threadIdx.x;

    const int x0 = (tid & 15) * 4;   // 16 tiles across
    const int y0 = (tid >> 4) * 4;   // 16 tiles down

    float sum[4][4];
#pragma unroll
    for (int i = 0; i < 4; ++i)
#pragma unroll
        for (int j = 0; j < 4; ++j) sum[i][j] = 0.0f;

    const float* imgB = img + (size_t)b * IC * N * N;
    const float* kerO = ker + (size_t)oc * IC * 49;
    const int ic0 = chunk * IC_CHUNK;

    for (int ic = ic0; ic < ic0 + IC_CHUNK; ++ic) {
        const float* src = imgB + ic * N * N;

        __syncthreads();   // previous iteration's reads of H are done

        // ---- stage interior: H[yy][4..67] = img[(yy-2)%64][0..63], float4 ----
        for (int f = tid; f < 70 * 16; f += 256) {
            int yy = f >> 4;
            int c4 = (f & 15) * 4;
            int sy = yy - 2;
            if (sy < 0)  sy += 64;
            if (sy >= 64) sy -= 64;
            const float4 v = *(const float4*)(src + sy * 64 + c4);
            *(float4*)(&H[yy * LDS_STRIDE + 4 + c4]) = v;
        }
        // ---- halo cols xx in {2,3,68,69,70,71} -> img cols {62,63,0,1,2,3} ----
        for (int f = tid; f < 70 * 8; f += 256) {
            int yy = f >> 3;
            int h  = f & 7;
            if (h < 6) {
                int xx = (h < 2) ? (h + 2)  : (h + 66);
                int sc = (h < 2) ? (h + 62) : (h - 2);
                int sy = yy - 2;
                if (sy < 0)  sy += 64;
                if (sy >= 64) sy -= 64;
                H[yy * LDS_STRIDE + xx] = src[sy * 64 + sc];
            }
        }
        __syncthreads();

        // ---- wave-uniform kernel taps (flipped) -> scalar loads ----
        float kreg[49];
#pragma unroll
        for (int t = 0; t < 49; ++t) kreg[t] = kerO[ic * 49 + 48 - t];

        float acc[4][4];
#pragma unroll
        for (int i = 0; i < 4; ++i)
#pragma unroll
            for (int j = 0; j < 4; ++j) acc[i][j] = 0.0f;

        // window rows r = 0..9 (H rows y0..y0+9), 12-wide window per row
#pragma unroll
        for (int r = 0; r < 10; ++r) {
            const float* row = &H[(y0 + r) * LDS_STRIDE + x0];
            const float4 wa = *(const float4*)(row);
            const float4 wb = *(const float4*)(row + 4);
            const float4 wc = *(const float4*)(row + 8);
            const float w[12] = {wa.x, wa.y, wa.z, wa.w,
                                 wb.x, wb.y, wb.z, wb.w,
                                 wc.x, wc.y, wc.z, wc.w};
#pragma unroll
            for (int a = 0; a < 7; ++a) {
                const int yd = r - a;          // output row within tile
                if (yd < 0 || yd > 3) continue;
#pragma unroll
                for (int q = 0; q < 7; ++q) {
                    const float k = kreg[a * 7 + q];
#pragma unroll
                    for (int xi = 0; xi < 4; ++xi)
                        acc[yd][xi] += k * w[xi + q + 2];
                }
            }
        }

#pragma unroll
        for (int i = 0; i < 4; ++i)
#pragma unroll
            for (int j = 0; j < 4; ++j) sum[i][j] += fabsf(acc[i][j]);
    }

    float* o = out + (((size_t)b * OC + oc) * N + y0) * N + x0;
#pragma unroll
    for (int i = 0; i < 4; ++i)
#pragma unroll
        for (int j = 0; j < 4; ++j)
            atomicAdd(o + (size_t)i * N + j, sum[i][j]);
}

} // namespace

extern "C" void kernel_launch(void* const* d_in, const int* in_sizes, int n_in,
                              void* d_out, int out_size, void* d_ws, size_t ws_size,
                              hipStream_t stream) {
    const float* img = (const float*)d_in[0];   // [8][32][64][64]
    const float* ker = (const float*)d_in[1];   // [64][32][7][7]
    float* out = (float*)d_out;                 // [8][64][64][64]
    hipMemsetAsync(out, 0, (size_t)out_size * sizeof(float), stream);
    optconv_abs_sum<<<dim3(8 * 64 * 4), dim3(256), 0, stream>>>(img, ker, out);
}

// Round 3
// 146.198 us; speedup vs baseline: 1.4251x; 1.4251x over previous
//
#include <hip/hip_runtime.h>

typedef __attribute__((ext_vector_type(8))) short short8;
typedef __attribute__((ext_vector_type(4))) float f32x4;

namespace {

__device__ __forceinline__ unsigned short f2bf(float f) {
    unsigned int u = __float_as_uint(f);
    u += 0x7fffu + ((u >> 16) & 1u);     // RNE to bf16 (inputs are finite/normal)
    return (unsigned short)(u >> 16);
}

// ---------------------------------------------------------------------------
// Prep: Bp[ic][oc][k] (bf16), k = a*8+q; val = ker[oc][ic][6-a][6-q] for a,q<7
// else 0 (the zero columns kill the garbage taps in A). Fragment-ordered so a
// lane's B-frag is one aligned dwordx4: uint4 index = (ic*64+oc)*8 + 4*t + g.
// ---------------------------------------------------------------------------
__global__ void prep_B(const float* __restrict__ ker, uint4* __restrict__ BpV) {
    int t = blockIdx.x * 256 + threadIdx.x;       // 16384 threads
    int a  = t & 7;
    int oc = (t >> 3) & 63;
    int ic = t >> 9;
    unsigned int d[4] = {0u, 0u, 0u, 0u};
    if (a < 7) {
        const float* row = ker + ((oc * 32 + ic) * 49) + (6 - a) * 7;  // row (6-a)
        float v[8];
#pragma unroll
        for (int q = 0; q < 7; ++q) v[q] = row[6 - q];
        v[7] = 0.0f;
#pragma unroll
        for (int j = 0; j < 4; ++j)
            d[j] = (unsigned int)f2bf(v[2 * j]) | ((unsigned int)f2bf(v[2 * j + 1]) << 16);
    }
    BpV[(ic * 64 + oc) * 8 + a] = make_uint4(d[0], d[1], d[2], d[3]);
}

// ---------------------------------------------------------------------------
// Main: per (b, 2-row chunk, ic-half). out[y,x] per (oc,ic) =
//   sum_{a,q} ker[6-a][6-q] * img[(y-2+a)%64][(x-2+q)%64]  -> GEMM M=pix,N=oc,K=64
// H2 dword p (pitch 80) = pack(bf16(img col (p-2)%64), bf16(img col (p-1)%64))
// A-frag (m=lane&15 -> pixel x, g=lane>>4, kstep t): row r = rowoff+g+4t,
//   4 dwords at H2[r*80 + x + {0,2,4,6}]  (ds_read2_b32, 2-way banks).
// ---------------------------------------------------------------------------
__global__ __launch_bounds__(256, 2) void conv_mfma(
    const float* __restrict__ img,          // [8][32][64][64]
    const uint4* __restrict__ BpV,          // prepped B frags
    float* __restrict__ out)                // [8][64][64][64], pre-zeroed
{
    __shared__ unsigned int H2[9 * 80];

    const int bid   = blockIdx.x;           // 512 = b(8) x chunk(32) x ih(2)
    const int ih    = bid & 1;
    const int chunk = (bid >> 1) & 31;
    const int b     = bid >> 6;
    const int y0    = chunk * 2;
    const int tid   = threadIdx.x;
    const int lane  = tid & 63;
    const int w     = tid >> 6;
    const int n     = lane & 15;            // A-m / B-n / D-col
    const int g     = lane >> 4;            // k-group / D-row-group
    const int rowoff = w >> 1;              // wave's image row within chunk
    const int xbase  = 32 * (w & 1);

    f32x4 acc[2][4];
#pragma unroll
    for (int mt = 0; mt < 2; ++mt)
#pragma unroll
        for (int nt = 0; nt < 4; ++nt) acc[mt][nt] = (f32x4){0.f, 0.f, 0.f, 0.f};

    const float* imgB = img + (size_t)(b * 32) * 4096;
    const int ic0 = ih * 16;

    // prefetch plane ic0 into registers
    float pv[3];
#pragma unroll
    for (int j = 0; j < 3; ++j) {
        int f = tid + j * 256;
        if (f < 576) {
            int r = (y0 - 2 + (f >> 6)) & 63;
            pv[j] = imgB[ic0 * 4096 + r * 64 + (f & 63)];
        }
    }

    for (int ici = 0; ici < 16; ++ici) {
        const int ic = ic0 + ici;

        // B fragments for this ic (L2-resident, issued early)
        short8 bf[4][2];
#pragma unroll
        for (int nt = 0; nt < 4; ++nt)
#pragma unroll
            for (int t = 0; t < 2; ++t)
                bf[nt][t] = __builtin_bit_cast(short8,
                    BpV[(ic * 64 + 16 * nt + n) * 8 + 4 * t + g]);

        __syncthreads();                    // previous compute done with H2
        // ---- write staged plane (bf16-pair format, wrap-aware) ----
        {
            unsigned short* Hs = (unsigned short*)H2;
#pragma unroll
            for (int j = 0; j < 3; ++j) {
                int f = tid + j * 256;
                if (f < 576) {
                    int r = f >> 6, c = f & 63;
                    unsigned short h = f2bf(pv[j]);
                    int base = r * 160;
                    Hs[base + 2 * (c + 2)]     = h;   // low  of p=c+2
                    Hs[base + 2 * (c + 1) + 1] = h;   // high of p=c+1
                    if (c >= 62) Hs[base + 2 * (c - 62)]     = h;
                    if (c <= 3)  Hs[base + 2 * (c + 66)]     = h;
                    if (c == 63) Hs[base + 1]                = h;
                    if (c <= 4)  Hs[base + 2 * (c + 65) + 1] = h;
                }
            }
        }
        __syncthreads();

        // ---- prefetch next plane (hidden behind MFMA phase) ----
        if (ici < 15) {
            const float* p = imgB + (ic + 1) * 4096;
#pragma unroll
            for (int j = 0; j < 3; ++j) {
                int f = tid + j * 256;
                if (f < 576) {
                    int r = (y0 - 2 + (f >> 6)) & 63;
                    pv[j] = p[r * 64 + (f & 63)];
                }
            }
        }

        // ---- compute: 2 m-tiles x 4 oc-tiles x 2 k-steps ----
#pragma unroll
        for (int mt = 0; mt < 2; ++mt) {
            const int xs = xbase + 16 * mt;
            const int base0 = (rowoff + g) * 80 + xs + n;
            const int base1 = base0 + 4 * 80;
            uint4 a0v = make_uint4(H2[base0], H2[base0 + 2], H2[base0 + 4], H2[base0 + 6]);
            uint4 a1v = make_uint4(H2[base1], H2[base1 + 2], H2[base1 + 4], H2[base1 + 6]);
            short8 a0 = __builtin_bit_cast(short8, a0v);
            short8 a1 = __builtin_bit_cast(short8, a1v);
#pragma unroll
            for (int nt = 0; nt < 4; ++nt) {
                f32x4 d = (f32x4){0.f, 0.f, 0.f, 0.f};
                d = __builtin_amdgcn_mfma_f32_16x16x32_bf16(a0, bf[nt][0], d, 0, 0, 0);
                d = __builtin_amdgcn_mfma_f32_16x16x32_bf16(a1, bf[nt][1], d, 0, 0, 0);
#pragma unroll
                for (int i = 0; i < 4; ++i)
                    acc[mt][nt][i] += __builtin_fabsf(d[i]);   // v_add_f32 with |mod|
            }
        }
    }

    // ---- epilogue: one atomicAdd per element (2 ic-halves share out) ----
    const int y = y0 + rowoff;
#pragma unroll
    for (int mt = 0; mt < 2; ++mt) {
        const int xs = xbase + 16 * mt;
#pragma unroll
        for (int nt = 0; nt < 4; ++nt) {
            const int oc = 16 * nt + n;
            float* o = out + (((size_t)(b * 64 + oc) * 64) + y) * 64 + xs + 4 * g;
#pragma unroll
            for (int i = 0; i < 4; ++i) atomicAdd(o + i, acc[mt][nt][i]);
        }
    }
}

} // namespace

extern "C" void kernel_launch(void* const* d_in, const int* in_sizes, int n_in,
                              void* d_out, int out_size, void* d_ws, size_t ws_size,
                              hipStream_t stream) {
    const float* img = (const float*)d_in[0];   // [8][32][64][64]
    const float* ker = (const float*)d_in[1];   // [64][32][7][7]
    float* out = (float*)d_out;                 // [8][64][64][64]
    uint4* BpV = (uint4*)d_ws;                  // 256 KB fragment-ordered B

    hipMemsetAsync(out, 0, (size_t)out_size * sizeof(float), stream);
    prep_B<<<dim3(64), dim3(256), 0, stream>>>(ker, BpV);
    conv_mfma<<<dim3(512), dim3(256), 0, stream>>>(img, BpV, out);
}

// Round 4
// 96.638 us; speedup vs baseline: 2.1560x; 1.5128x over previous
//
#include <hip/hip_runtime.h>

typedef __attribute__((ext_vector_type(8))) short short8;
typedef __attribute__((ext_vector_type(4))) float f32x4;

namespace {

__device__ __forceinline__ unsigned short f2bf(float f) {
    unsigned int u = __float_as_uint(f);
    u += 0x7fffu + ((u >> 16) & 1u);     // RNE to bf16
    return (unsigned short)(u >> 16);
}

// ---------------------------------------------------------------------------
// B2: lane-major fragment-coalesced taps. uint4 slot = (ic*8 + nt*2 + t)*64 + lane,
// lane = g*16 + n. Holds 8 bf16 taps (q=0..7, flipped; q==7 zero) of tap-row
// a = 4t+g (flipped; a==7 zero) for oc = 16*nt+n. A wave's fragment load is one
// fully-coalesced global_load_dwordx4 (64 lanes x 16 B = 1 KB contiguous).
// ---------------------------------------------------------------------------
__global__ void prep_B(const float* __restrict__ ker, uint4* __restrict__ B2) {
    int t  = blockIdx.x * 256 + threadIdx.x;   // 16384 threads
    int a  = t & 7;
    int oc = (t >> 3) & 63;
    int ic = t >> 9;
    unsigned int d[4] = {0u, 0u, 0u, 0u};
    if (a < 7) {
        const float* row = ker + ((oc * 32 + ic) * 49) + (6 - a) * 7;
        float v[8];
#pragma unroll
        for (int q = 0; q < 7; ++q) v[q] = row[6 - q];
        v[7] = 0.0f;
#pragma unroll
        for (int j = 0; j < 4; ++j)
            d[j] = (unsigned int)f2bf(v[2 * j]) | ((unsigned int)f2bf(v[2 * j + 1]) << 16);
    }
    int nt = oc >> 4, n = oc & 15, ts = a >> 2, g = a & 3;
    B2[(ic * 8 + nt * 2 + ts) * 64 + g * 16 + n] = make_uint4(d[0], d[1], d[2], d[3]);
}

// 9-row halo window (rows y0-2 .. y0+6, wrapped) of one plane, 576 floats
__device__ __forceinline__ void load_pv(float pv[3], const float* __restrict__ plane,
                                        int y0, int tid) {
#pragma unroll
    for (int j = 0; j < 3; ++j) {
        int f = tid + j * 256;
        if (f < 576) {
            int r = (y0 - 2 + (f >> 6)) & 63;
            pv[j] = plane[r * 64 + (f & 63)];
        }
    }
}

// H2 dword p (pitch 80) = pack(bf16 col (p-2)%64, bf16 col (p-1)%64)
__device__ __forceinline__ void stage_plane(unsigned int* __restrict__ Hb,
                                            const float pv[3], int tid) {
    unsigned short* Hs = (unsigned short*)Hb;
#pragma unroll
    for (int j = 0; j < 3; ++j) {
        int f = tid + j * 256;
        if (f < 576) {
            int r = f >> 6, c = f & 63;
            unsigned short h = f2bf(pv[j]);
            int base = r * 160;
            Hs[base + 2 * (c + 2)]     = h;   // low  of dword c+2
            Hs[base + 2 * (c + 1) + 1] = h;   // high of dword c+1
            if (c >= 62) Hs[base + 2 * (c - 62)]     = h;   // wrap left lows
            if (c <= 3)  Hs[base + 2 * (c + 66)]     = h;   // wrap right lows
            if (c == 63) Hs[base + 1]                = h;   // high of dword 0
            if (c <= 4)  Hs[base + 2 * (c + 65) + 1] = h;   // wrap right highs
        }
    }
}

__device__ __forceinline__ void load_B(uint4 bf[8], const uint4* __restrict__ B2,
                                       int ic, int lane) {
#pragma unroll
    for (int q = 0; q < 8; ++q)             // q = nt*2 + t
        bf[q] = B2[(ic * 8 + q) * 64 + lane];
}

// D = A(taps: m=oc) x B(img: n=pixel). Img frag: lane holds row a=g (+4t),
// cols x-2..x+5 for x = xs+n -> 4 dwords at +0,2,4,6 (2-way banks, free).
__device__ __forceinline__ void compute_ic(const unsigned int* __restrict__ Hc,
                                           const uint4 bf[8], f32x4 acc[2][4],
                                           int rowoff, int xbase, int n, int g) {
#pragma unroll
    for (int mt = 0; mt < 2; ++mt) {
        const int xs = xbase + 16 * mt;
        const int b0 = (rowoff + g) * 80 + xs + n;
        const int b1 = b0 + 320;
        uint4 i0 = make_uint4(Hc[b0], Hc[b0 + 2], Hc[b0 + 4], Hc[b0 + 6]);
        uint4 i1 = make_uint4(Hc[b1], Hc[b1 + 2], Hc[b1 + 4], Hc[b1 + 6]);
        short8 f0 = __builtin_bit_cast(short8, i0);
        short8 f1 = __builtin_bit_cast(short8, i1);
#pragma unroll
        for (int nt = 0; nt < 4; ++nt) {
            f32x4 d = (f32x4){0.f, 0.f, 0.f, 0.f};
            d = __builtin_amdgcn_mfma_f32_16x16x32_bf16(
                    __builtin_bit_cast(short8, bf[2 * nt]),     f0, d, 0, 0, 0);
            d = __builtin_amdgcn_mfma_f32_16x16x32_bf16(
                    __builtin_bit_cast(short8, bf[2 * nt + 1]), f1, d, 0, 0, 0);
#pragma unroll
            for (int i = 0; i < 4; ++i)
                acc[mt][nt][i] += __builtin_fabsf(d[i]);
        }
    }
}

__global__ __launch_bounds__(256, 2) void conv_mfma(
    const float* __restrict__ img,          // [8][32][64][64]
    const uint4* __restrict__ B2,           // prepped taps
    float* __restrict__ out)                // [8][64][64][64], pre-zeroed
{
    __shared__ unsigned int H2[2][9 * 80];

    const int bid   = blockIdx.x;           // 512 = b(8) x chunk(32) x ih(2)
    const int ih    = bid & 1;
    const int chunk = (bid >> 1) & 31;
    const int b     = bid >> 6;
    const int y0    = chunk * 2;
    const int tid   = threadIdx.x;
    const int lane  = tid & 63;
    const int w     = tid >> 6;
    const int n     = lane & 15;
    const int g     = lane >> 4;
    const int rowoff = w >> 1;
    const int xbase  = 32 * (w & 1);

    f32x4 acc[2][4];
#pragma unroll
    for (int mt = 0; mt < 2; ++mt)
#pragma unroll
        for (int nt = 0; nt < 4; ++nt) acc[mt][nt] = (f32x4){0.f, 0.f, 0.f, 0.f};

    const float* imgB = img + (size_t)(b * 32) * 4096;
    const int ic0 = ih * 16;

    uint4 bfA[8], bfB[8];
    float pv[3];

    // prologue: plane ic0 staged, taps(ic0) in bfA, pv <- plane ic0+1
    load_pv(pv, imgB + ic0 * 4096, y0, tid);
    load_B(bfA, B2, ic0, lane);
    stage_plane(H2[0], pv, tid);
    load_pv(pv, imgB + (ic0 + 1) * 4096, y0, tid);
    __syncthreads();

    for (int p = 0; p < 8; ++p) {
        const int ic = ic0 + 2 * p;
        // even iter: compute(H2[0], bfA); stage ic+1 -> H2[1]; prefetch ic+2
        load_B(bfB, B2, ic + 1, lane);
        stage_plane(H2[1], pv, tid);
        if (p < 7) load_pv(pv, imgB + (ic + 2) * 4096, y0, tid);
        compute_ic(H2[0], bfA, acc, rowoff, xbase, n, g);
        __syncthreads();

        // odd iter: compute(H2[1], bfB); stage ic+2 -> H2[0]; prefetch ic+3
        if (p < 7) {
            load_B(bfA, B2, ic + 2, lane);
            stage_plane(H2[0], pv, tid);
            load_pv(pv, imgB + (ic + 3) * 4096, y0, tid);
        }
        compute_ic(H2[1], bfB, acc, rowoff, xbase, n, g);
        __syncthreads();
    }

    // epilogue: D col = lane&15 = x -> 16-lane-contiguous atomics (4 lines/instr)
    const int y = y0 + rowoff;
#pragma unroll
    for (int mt = 0; mt < 2; ++mt) {
        const int xt = xbase + 16 * mt;
#pragma unroll
        for (int nt = 0; nt < 4; ++nt) {
            float* o = out + (((size_t)(b * 64 + 16 * nt + 4 * g) * 64) + y) * 64 + xt + n;
#pragma unroll
            for (int i = 0; i < 4; ++i)
                atomicAdd(o + (size_t)i * 4096, acc[mt][nt][i]);   // +1 oc per i
        }
    }
}

} // namespace

extern "C" void kernel_launch(void* const* d_in, const int* in_sizes, int n_in,
                              void* d_out, int out_size, void* d_ws, size_t ws_size,
                              hipStream_t stream) {
    const float* img = (const float*)d_in[0];   // [8][32][64][64]
    const float* ker = (const float*)d_in[1];   // [64][32][7][7]
    float* out = (float*)d_out;                 // [8][64][64][64]
    uint4* B2 = (uint4*)d_ws;                   // 256 KB lane-major taps

    hipMemsetAsync(out, 0, (size_t)out_size * sizeof(float), stream);
    prep_B<<<dim3(64), dim3(256), 0, stream>>>(ker, B2);
    conv_mfma<<<dim3(512), dim3(256), 0, stream>>>(img, B2, out);
}

// Round 5
// 94.772 us; speedup vs baseline: 2.1984x; 1.0197x over previous
//
#include <hip/hip_runtime.h>

typedef __attribute__((ext_vector_type(8))) short short8;
typedef __attribute__((ext_vector_type(4))) float f32x4;

namespace {

__device__ __forceinline__ unsigned short f2bf(float f) {
    unsigned int u = __float_as_uint(f);
    u += 0x7fffu + ((u >> 16) & 1u);     // RNE to bf16
    return (unsigned short)(u >> 16);
}

// ---------------------------------------------------------------------------
// B2: lane-major fragment-coalesced taps. uint4 slot = (ic*8 + nt*2 + t)*64 + lane,
// lane = g*16 + n. 8 bf16 taps (q=0..7 flipped, q==7 zero) of tap-row a = 4t+g
// (flipped, a==7 zero) for oc = 16*nt+n. One wave B-frag load = one coalesced
// global_load_dwordx4 of 1 KB.
// ---------------------------------------------------------------------------
__global__ void prep_B(const float* __restrict__ ker, uint4* __restrict__ B2) {
    int t  = blockIdx.x * 256 + threadIdx.x;   // 16384 threads
    int a  = t & 7;
    int oc = (t >> 3) & 63;
    int ic = t >> 9;
    unsigned int d[4] = {0u, 0u, 0u, 0u};
    if (a < 7) {
        const float* row = ker + ((oc * 32 + ic) * 49) + (6 - a) * 7;
        float v[8];
#pragma unroll
        for (int q = 0; q < 7; ++q) v[q] = row[6 - q];
        v[7] = 0.0f;
#pragma unroll
        for (int j = 0; j < 4; ++j)
            d[j] = (unsigned int)f2bf(v[2 * j]) | ((unsigned int)f2bf(v[2 * j + 1]) << 16);
    }
    int nt = oc >> 4, n = oc & 15, ts = a >> 2, g = a & 3;
    B2[(ic * 8 + nt * 2 + ts) * 64 + g * 16 + n] = make_uint4(d[0], d[1], d[2], d[3]);
}

// ---------------------------------------------------------------------------
// Conv: grid 1024 = b(8) x ih(4) x chunk(32); block = 4 waves, 2 output rows.
// All 8 planes (ic = ih*8 .. +7) staged to LDS up front, ONE barrier, then an
// uninterrupted MFMA loop. H dword p (pitch 80, plane stride 720) =
// pack(bf16 img col (p-2)%64, bf16 col (p-1)%64).
// ---------------------------------------------------------------------------
__global__ __launch_bounds__(256, 4) void conv_mfma(
    const float* __restrict__ img,          // [8][32][64][64]
    const uint4* __restrict__ B2,           // prepped taps
    float* __restrict__ out)                // [8][64][64][64], pre-zeroed
{
    __shared__ unsigned int H[8 * 9 * 80];  // 23040 B

    const int bid   = blockIdx.x;           // ((b*4 + ih)*32 + chunk)
    const int chunk = bid & 31;
    const int ih    = (bid >> 5) & 3;
    const int b     = bid >> 7;
    const int y0    = chunk * 2;
    const int tid   = threadIdx.x;
    const int lane  = tid & 63;
    const int w     = tid >> 6;             // 4 waves
    const int n     = lane & 15;
    const int g     = lane >> 4;
    const int rowoff = w >> 1;              // output row within chunk (0..1)
    const int xbase  = 32 * (w & 1);

    const float* base = img + ((size_t)(b * 32 + ih * 8)) * 4096;

    // ---- stage 8 planes: wave w owns planes 2w, 2w+1 (9 rows each) ----
    float v[18];
#pragma unroll
    for (int j = 0; j < 18; ++j) {
        const int pl = 2 * w + (j >= 9 ? 1 : 0);
        const int r  = (j >= 9) ? (j - 9) : j;
        const int row = (y0 - 2 + r) & 63;
        v[j] = base[pl * 4096 + row * 64 + lane];
    }
#pragma unroll
    for (int j = 0; j < 18; ++j) {
        const int pl = 2 * w + (j >= 9 ? 1 : 0);
        const int r  = (j >= 9) ? (j - 9) : j;
        const unsigned int h  = f2bf(v[j]);
        const unsigned int hn = (unsigned int)__shfl((int)h, (lane + 1) & 63);
        const unsigned int dw = h | (hn << 16);      // (col lane, col lane+1)
        const int idx = pl * 720 + r * 80;
        H[idx + lane + 2] = dw;                      // dword p = lane+2
        if (lane >= 62) H[idx + lane - 62] = dw;     // p = 0,1  (wrap left)
        if (lane <= 5)  H[idx + lane + 66] = dw;     // p = 66..71 (wrap right)
    }
    __syncthreads();                                 // the only barrier

    // ---- compute: 8 ic, no further syncs ----
    f32x4 acc[2][4];
#pragma unroll
    for (int mt = 0; mt < 2; ++mt)
#pragma unroll
        for (int nt = 0; nt < 4; ++nt) acc[mt][nt] = (f32x4){0.f, 0.f, 0.f, 0.f};

#pragma unroll 2
    for (int ic = 0; ic < 8; ++ic) {
        const int icg = ih * 8 + ic;
        uint4 bf[8];
#pragma unroll
        for (int q = 0; q < 8; ++q)                  // coalesced, L1-hot
            bf[q] = B2[(icg * 8 + q) * 64 + lane];

        const int base0 = ic * 720 + (rowoff + g) * 80 + n;
#pragma unroll
        for (int mt = 0; mt < 2; ++mt) {
            const int b0 = base0 + xbase + 16 * mt;
            const int b1 = b0 + 320;                 // +4 rows (k-tile 1)
            uint4 i0 = make_uint4(H[b0], H[b0 + 2], H[b0 + 4], H[b0 + 6]);
            uint4 i1 = make_uint4(H[b1], H[b1 + 2], H[b1 + 4], H[b1 + 6]);
            short8 f0 = __builtin_bit_cast(short8, i0);
            short8 f1 = __builtin_bit_cast(short8, i1);
#pragma unroll
            for (int nt = 0; nt < 4; ++nt) {
                f32x4 d = (f32x4){0.f, 0.f, 0.f, 0.f};
                d = __builtin_amdgcn_mfma_f32_16x16x32_bf16(
                        __builtin_bit_cast(short8, bf[2 * nt]),     f0, d, 0, 0, 0);
                d = __builtin_amdgcn_mfma_f32_16x16x32_bf16(
                        __builtin_bit_cast(short8, bf[2 * nt + 1]), f1, d, 0, 0, 0);
#pragma unroll
                for (int i = 0; i < 4; ++i)
                    acc[mt][nt][i] += __builtin_fabsf(d[i]);
            }
        }
    }

    // ---- epilogue: D row = oc-in-tile (4g+i), col = x (n) -> coalesced ----
    const int y = y0 + rowoff;
#pragma unroll
    for (int mt = 0; mt < 2; ++mt) {
        const int xt = xbase + 16 * mt;
#pragma unroll
        for (int nt = 0; nt < 4; ++nt) {
            float* o = out + (((size_t)(b * 64 + 16 * nt + 4 * g) * 64) + y) * 64 + xt + n;
#pragma unroll
            for (int i = 0; i < 4; ++i)
                atomicAdd(o + (size_t)i * 4096, acc[mt][nt][i]);
        }
    }
}

} // namespace

extern "C" void kernel_launch(void* const* d_in, const int* in_sizes, int n_in,
                              void* d_out, int out_size, void* d_ws, size_t ws_size,
                              hipStream_t stream) {
    const float* img = (const float*)d_in[0];   // [8][32][64][64]
    const float* ker = (const float*)d_in[1];   // [64][32][7][7]
    float* out = (float*)d_out;                 // [8][64][64][64]
    uint4* B2 = (uint4*)d_ws;                   // 256 KB lane-major taps

    hipMemsetAsync(out, 0, (size_t)out_size * sizeof(float), stream);
    prep_B<<<dim3(64), dim3(256), 0, stream>>>(ker, B2);
    conv_mfma<<<dim3(1024), dim3(256), 0, stream>>>(img, B2, out);
}

// Round 6
// 80.004 us; speedup vs baseline: 2.6042x; 1.1846x over previous
//
#include <hip/hip_runtime.h>

typedef __attribute__((ext_vector_type(8))) short short8;
typedef __attribute__((ext_vector_type(4))) float f32x4;

namespace {

__device__ __forceinline__ unsigned short f2bf(float f) {
    unsigned int u = __float_as_uint(f);
    u += 0x7fffu + ((u >> 16) & 1u);     // RNE to bf16
    return (unsigned short)(u >> 16);
}

// ---------------------------------------------------------------------------
// B2: lane-major fragment-coalesced taps. uint4 slot = (ic*8 + nt*2 + t)*64 + lane,
// lane = g*16 + n. 8 bf16 taps (q=0..7 flipped, q==7 zero) of tap-row a = 4t+g
// (flipped, a==7 zero) for oc = 16*nt+n. One wave B-frag load = one coalesced
// global_load_dwordx4 of 1 KB.
// ---------------------------------------------------------------------------
__global__ void prep_B(const float* __restrict__ ker, uint4* __restrict__ B2) {
    int t  = blockIdx.x * 256 + threadIdx.x;   // 16384 threads
    int a  = t & 7;
    int oc = (t >> 3) & 63;
    int ic = t >> 9;
    unsigned int d[4] = {0u, 0u, 0u, 0u};
    if (a < 7) {
        const float* row = ker + ((oc * 32 + ic) * 49) + (6 - a) * 7;
        float v[8];
#pragma unroll
        for (int q = 0; q < 7; ++q) v[q] = row[6 - q];
        v[7] = 0.0f;
#pragma unroll
        for (int j = 0; j < 4; ++j)
            d[j] = (unsigned int)f2bf(v[2 * j]) | ((unsigned int)f2bf(v[2 * j + 1]) << 16);
    }
    int nt = oc >> 4, n = oc & 15, ts = a >> 2, g = a & 3;
    B2[(ic * 8 + nt * 2 + ts) * 64 + g * 16 + n] = make_uint4(d[0], d[1], d[2], d[3]);
}

// ---------------------------------------------------------------------------
// Conv: grid 512 = b(8) x y(64). Block = 512 threads (8 waves) computes ONE
// output row x 64 x x 64 oc over ALL 32 ic -> plain coalesced stores, no
// atomics, no memset. Wave w: xq = w&3 (16-x quarter), ich = w>>2 (16-ic half);
// halves merge via an LDS partial buffer aliased onto the dead image tile.
// H dword p (pitch 80, plane stride 560) = pack(bf16 col (p-2)%64, col (p-1)%64)
// of window row r = image row (y-2+r)%64, r in [0,7). a==7 tap row reads pad
// (values killed by zero B columns).
// ---------------------------------------------------------------------------
__global__ __launch_bounds__(512, 4) void conv_mfma(
    const float* __restrict__ img,          // [8][32][64][64]
    const uint4* __restrict__ B2,           // prepped taps
    float* __restrict__ out)                // [8][64][64][64]
{
    __shared__ unsigned int H[18000];       // 32*560 = 17920 (+80 pad for a==7 reads)

    const int bid  = blockIdx.x;            // b*64 + y
    const int y    = bid & 63;
    const int b    = bid >> 6;
    const int tid  = threadIdx.x;
    const int lane = tid & 63;
    const int w    = tid >> 6;              // 8 waves
    const int xq   = w & 3;
    const int ich  = w >> 2;
    const int n    = lane & 15;
    const int g    = lane >> 4;
    const int x0   = xq * 16;

    const float* base = img + (size_t)b * 32 * 4096;

    // ---- stage: wave w owns planes 4w..4w+3, 7 rows each; col = lane ----
    float v[28];
#pragma unroll
    for (int j = 0; j < 28; ++j) {          // j/7, j%7 fold to constants
        const int pl  = 4 * w + j / 7;
        const int row = (y - 2 + (j % 7)) & 63;
        v[j] = base[pl * 4096 + row * 64 + lane];
    }
#pragma unroll
    for (int j = 0; j < 28; ++j) {
        const int pl = 4 * w + j / 7;
        const int r  = j % 7;
        const unsigned int h  = f2bf(v[j]);
        const unsigned int hn = (unsigned int)__shfl((int)h, (lane + 1) & 63);
        const unsigned int dw = h | (hn << 16);   // cols (lane, lane+1) -> dword lane+2
        const int idx = pl * 560 + r * 80;
        H[idx + lane + 2] = dw;
        if (lane >= 62) H[idx + lane - 62] = dw;  // wrap left  (p = 0,1)
        if (lane <= 5)  H[idx + lane + 66] = dw;  // wrap right (p = 66..71)
    }
    __syncthreads();                              // single staging barrier

    // ---- compute: 16 ic, uninterrupted ----
    f32x4 acc[4];
#pragma unroll
    for (int nt = 0; nt < 4; ++nt) acc[nt] = (f32x4){0.f, 0.f, 0.f, 0.f};

    const int ic0 = ich * 16;
#pragma unroll 4
    for (int ici = 0; ici < 16; ++ici) {
        const int ic = ic0 + ici;
        uint4 bf[8];
#pragma unroll
        for (int q = 0; q < 8; ++q)               // coalesced, L1/L2-hot
            bf[q] = B2[(ic * 8 + q) * 64 + lane];

        const int b0 = ic * 560 + g * 80 + x0 + n;      // tap row a = g
        const int b1 = b0 + 320;                        // tap row a = g+4
        uint4 i0 = make_uint4(H[b0], H[b0 + 2], H[b0 + 4], H[b0 + 6]);
        uint4 i1 = make_uint4(H[b1], H[b1 + 2], H[b1 + 4], H[b1 + 6]);
        short8 f0 = __builtin_bit_cast(short8, i0);
        short8 f1 = __builtin_bit_cast(short8, i1);
#pragma unroll
        for (int nt = 0; nt < 4; ++nt) {
            f32x4 d = (f32x4){0.f, 0.f, 0.f, 0.f};
            d = __builtin_amdgcn_mfma_f32_16x16x32_bf16(
                    __builtin_bit_cast(short8, bf[2 * nt]),     f0, d, 0, 0, 0);
            d = __builtin_amdgcn_mfma_f32_16x16x32_bf16(
                    __builtin_bit_cast(short8, bf[2 * nt + 1]), f1, d, 0, 0, 0);
#pragma unroll
            for (int i = 0; i < 4; ++i)
                acc[nt][i] += __builtin_fabsf(d[i]);
        }
    }

    // ---- merge ic-halves through LDS (aliases dead image tile), store ----
    __syncthreads();                              // everyone done reading H
    float* P = (float*)H;                         // 64 x * 65 pitch * 64 oc region
    if (ich == 1) {
#pragma unroll
        for (int nt = 0; nt < 4; ++nt)
#pragma unroll
            for (int i = 0; i < 4; ++i)
                P[(x0 + n) * 65 + 16 * nt + 4 * g + i] = acc[nt][i];
    }
    __syncthreads();
    if (ich == 0) {
        float* o = out + (size_t)b * 64 * 4096 + y * 64;
#pragma unroll
        for (int nt = 0; nt < 4; ++nt)
#pragma unroll
            for (int i = 0; i < 4; ++i) {
                const int oc = 16 * nt + 4 * g + i;
                o[(size_t)oc * 4096 + x0 + n] =
                    acc[nt][i] + P[(x0 + n) * 65 + oc];
            }
    }
}

} // namespace

extern "C" void kernel_launch(void* const* d_in, const int* in_sizes, int n_in,
                              void* d_out, int out_size, void* d_ws, size_t ws_size,
                              hipStream_t stream) {
    const float* img = (const float*)d_in[0];   // [8][32][64][64]
    const float* ker = (const float*)d_in[1];   // [64][32][7][7]
    float* out = (float*)d_out;                 // [8][64][64][64]
    uint4* B2 = (uint4*)d_ws;                   // 256 KB lane-major taps

    prep_B<<<dim3(64), dim3(256), 0, stream>>>(ker, B2);
    conv_mfma<<<dim3(512), dim3(512), 0, stream>>>(img, B2, out);
}

// Round 7
// 74.620 us; speedup vs baseline: 2.7921x; 1.0722x over previous
//
#include <hip/hip_runtime.h>

typedef __attribute__((ext_vector_type(8))) short short8;
typedef __attribute__((ext_vector_type(4))) float f32x4;

namespace {

__device__ __forceinline__ unsigned short f2bf(float f) {
    unsigned int u = __float_as_uint(f);
    u += 0x7fffu + ((u >> 16) & 1u);     // RNE to bf16
    return (unsigned short)(u >> 16);
}

// ---------------------------------------------------------------------------
// B2: lane-major fragment-coalesced taps. uint4 slot = (ic*8 + nt*2 + t)*64 + lane,
// lane = g*16 + n. 8 bf16 taps (q=0..7 flipped, q==7 zero) of tap-row a = 4t+g
// (flipped, a==7 zero) for oc = 16*nt+n. One wave B-frag load = one coalesced
// global_load_dwordx4 of 1 KB.
// ---------------------------------------------------------------------------
__global__ void prep_B(const float* __restrict__ ker, uint4* __restrict__ B2) {
    int t  = blockIdx.x * 256 + threadIdx.x;   // 16384 threads
    int a  = t & 7;
    int oc = (t >> 3) & 63;
    int ic = t >> 9;
    unsigned int d[4] = {0u, 0u, 0u, 0u};
    if (a < 7) {
        const float* row = ker + ((oc * 32 + ic) * 49) + (6 - a) * 7;
        float v[8];
#pragma unroll
        for (int q = 0; q < 7; ++q) v[q] = row[6 - q];
        v[7] = 0.0f;
#pragma unroll
        for (int j = 0; j < 4; ++j)
            d[j] = (unsigned int)f2bf(v[2 * j]) | ((unsigned int)f2bf(v[2 * j + 1]) << 16);
    }
    int nt = oc >> 4, n = oc & 15, ts = a >> 2, g = a & 3;
    B2[(ic * 8 + nt * 2 + ts) * 64 + g * 16 + n] = make_uint4(d[0], d[1], d[2], d[3]);
}

// ---------------------------------------------------------------------------
// Conv: grid 512 = b(8) x y(64); block = 512 threads (8 waves), one output row.
// Wave w: xh = w&1 (32-px half), icg = w>>1 (8-ic group). Per ic a wave loads
// 8 tap-frags and fires 16 MFMAs (2 m-tiles) -> tap bytes amortized 4x vs R6.
// 4 partials/output merged via a 2-phase LDS tree (no atomics, no memset).
// H dword p (pitch 80, plane stride 560) = pack(bf16 col (p-2)%64, col (p-1)%64),
// window row r = image row (y-2+r)%64, r in [0,7); a==7 reads pad, killed by
// zero B columns.
// ---------------------------------------------------------------------------
__global__ __launch_bounds__(512, 4) void conv_mfma(
    const float* __restrict__ img,          // [8][32][64][64]
    const uint4* __restrict__ B2,           // prepped taps
    float* __restrict__ out)                // [8][64][64][64]
{
    __shared__ unsigned int H[18000];       // 32*560 = 17920 (+80 pad for a==7 reads)

    const int bid  = blockIdx.x;            // b*64 + y
    const int y    = bid & 63;
    const int b    = bid >> 6;
    const int tid  = threadIdx.x;
    const int lane = tid & 63;
    const int w    = tid >> 6;              // 8 waves
    const int xh   = w & 1;                 // x half (32 px)
    const int icg  = w >> 1;                // ic group (8 ic)
    const int n    = lane & 15;
    const int g    = lane >> 4;

    const float* base = img + (size_t)b * 32 * 4096;

    // ---- stage: wave w owns planes 4w..4w+3, 7 rows each; col = lane ----
    float v[28];
#pragma unroll
    for (int j = 0; j < 28; ++j) {          // j/7, j%7 fold to constants
        const int pl  = 4 * w + j / 7;
        const int row = (y - 2 + (j % 7)) & 63;
        v[j] = base[pl * 4096 + row * 64 + lane];
    }
#pragma unroll
    for (int j = 0; j < 28; ++j) {
        const int pl = 4 * w + j / 7;
        const int r  = j % 7;
        const unsigned int h  = f2bf(v[j]);
        const unsigned int hn = (unsigned int)__shfl((int)h, (lane + 1) & 63);
        const unsigned int dw = h | (hn << 16);   // cols (lane, lane+1) -> dword lane+2
        const int idx = pl * 560 + r * 80;
        H[idx + lane + 2] = dw;
        if (lane >= 62) H[idx + lane - 62] = dw;  // wrap left  (p = 0,1)
        if (lane <= 5)  H[idx + lane + 66] = dw;  // wrap right (p = 66..71)
    }
    __syncthreads();                              // staging barrier

    // ---- compute: 8 ic x 2 m-tiles, uninterrupted ----
    f32x4 acc[2][4];
#pragma unroll
    for (int mt = 0; mt < 2; ++mt)
#pragma unroll
        for (int nt = 0; nt < 4; ++nt) acc[mt][nt] = (f32x4){0.f, 0.f, 0.f, 0.f};

    const int ic0 = icg * 8;
#pragma unroll 2
    for (int ici = 0; ici < 8; ++ici) {
        const int ic = ic0 + ici;
        uint4 bf[8];
#pragma unroll
        for (int q = 0; q < 8; ++q)               // coalesced, L1/L2-hot
            bf[q] = B2[(ic * 8 + q) * 64 + lane];

#pragma unroll
        for (int mt = 0; mt < 2; ++mt) {
            const int x0 = 32 * xh + 16 * mt;
            const int b0 = ic * 560 + g * 80 + x0 + n;  // tap row a = g
            const int b1 = b0 + 320;                    // tap row a = g+4
            uint4 i0 = make_uint4(H[b0], H[b0 + 2], H[b0 + 4], H[b0 + 6]);
            uint4 i1 = make_uint4(H[b1], H[b1 + 2], H[b1 + 4], H[b1 + 6]);
            short8 f0 = __builtin_bit_cast(short8, i0);
            short8 f1 = __builtin_bit_cast(short8, i1);
#pragma unroll
            for (int nt = 0; nt < 4; ++nt) {
                f32x4 d = (f32x4){0.f, 0.f, 0.f, 0.f};
                d = __builtin_amdgcn_mfma_f32_16x16x32_bf16(
                        __builtin_bit_cast(short8, bf[2 * nt]),     f0, d, 0, 0, 0);
                d = __builtin_amdgcn_mfma_f32_16x16x32_bf16(
                        __builtin_bit_cast(short8, bf[2 * nt + 1]), f1, d, 0, 0, 0);
#pragma unroll
                for (int i = 0; i < 4; ++i)
                    acc[mt][nt][i] += __builtin_fabsf(d[i]);
            }
        }
    }

    // ---- merge 4 ic-group partials via LDS tree (aliases dead H) ----
    __syncthreads();                              // all compute done with H
    float* P = (float*)H;                         // 2 regions of 64*65 floats
    // phase 1: icg 1 and 3 publish
    if (icg & 1) {
        float* R = P + (icg >> 1) * 4160;         // icg1 -> R0, icg3 -> R1
#pragma unroll
        for (int mt = 0; mt < 2; ++mt)
#pragma unroll
            for (int nt = 0; nt < 4; ++nt)
#pragma unroll
                for (int i = 0; i < 4; ++i)
                    R[(16 * nt + 4 * g + i) * 65 + 32 * xh + 16 * mt + n] = acc[mt][nt][i];
    }
    __syncthreads();
    // phase 2a: icg0 += R0 (keeps in reg); icg2 += R1, publishes sum to R1
    if (icg == 0 || icg == 2) {
        float* R = P + (icg >> 1) * 4160;
#pragma unroll
        for (int mt = 0; mt < 2; ++mt)
#pragma unroll
            for (int nt = 0; nt < 4; ++nt)
#pragma unroll
                for (int i = 0; i < 4; ++i)
                    acc[mt][nt][i] += R[(16 * nt + 4 * g + i) * 65 + 32 * xh + 16 * mt + n];
    }
    if (icg == 2) {
        float* R = P + 4160;
#pragma unroll
        for (int mt = 0; mt < 2; ++mt)
#pragma unroll
            for (int nt = 0; nt < 4; ++nt)
#pragma unroll
                for (int i = 0; i < 4; ++i)
                    R[(16 * nt + 4 * g + i) * 65 + 32 * xh + 16 * mt + n] = acc[mt][nt][i];
    }
    __syncthreads();
    // phase 2b: icg0 adds icg2+icg3 sum and stores (coalesced 16-lane runs)
    if (icg == 0) {
        float* R = P + 4160;
        float* o = out + (size_t)b * 64 * 4096 + y * 64;
#pragma unroll
        for (int mt = 0; mt < 2; ++mt) {
            const int x0 = 32 * xh + 16 * mt;
#pragma unroll
            for (int nt = 0; nt < 4; ++nt)
#pragma unroll
                for (int i = 0; i < 4; ++i) {
                    const int oc = 16 * nt + 4 * g + i;
                    o[(size_t)oc * 4096 + x0 + n] =
                        acc[mt][nt][i] + R[oc * 65 + x0 + n];
                }
        }
    }
}

} // namespace

extern "C" void kernel_launch(void* const* d_in, const int* in_sizes, int n_in,
                              void* d_out, int out_size, void* d_ws, size_t ws_size,
                              hipStream_t stream) {
    const float* img = (const float*)d_in[0];   // [8][32][64][64]
    const float* ker = (const float*)d_in[1];   // [64][32][7][7]
    float* out = (float*)d_out;                 // [8][64][64][64]
    uint4* B2 = (uint4*)d_ws;                   // 256 KB lane-major taps

    prep_B<<<dim3(64), dim3(256), 0, stream>>>(ker, B2);
    conv_mfma<<<dim3(512), dim3(512), 0, stream>>>(img, B2, out);
}

// Round 8
// 74.206 us; speedup vs baseline: 2.8077x; 1.0056x over previous
//
#include <hip/hip_runtime.h>

typedef __attribute__((ext_vector_type(8))) short short8;
typedef __attribute__((ext_vector_type(4))) float f32x4;

namespace {

__device__ __forceinline__ unsigned short f2bf(float f) {
    unsigned int u = __float_as_uint(f);
    u += 0x7fffu + ((u >> 16) & 1u);     // RNE to bf16
    return (unsigned short)(u >> 16);
}

// ---------------------------------------------------------------------------
// B2: lane-major fragment-coalesced taps. uint4 slot = (ic*8 + ot*2 + kt)*64 + lane,
// lane = g*16 + n. 8 bf16 taps (q flipped, q==7 zero) of tap-row a = 4kt+g
// (flipped, a==7 zero) for oc = 16*ot+n. One wave B-frag load = one coalesced
// 1 KB global_load_dwordx4.
// ---------------------------------------------------------------------------
__global__ void prep_B(const float* __restrict__ ker, uint4* __restrict__ B2) {
    int t  = blockIdx.x * 256 + threadIdx.x;   // 16384 threads
    int a  = t & 7;
    int oc = (t >> 3) & 63;
    int ic = t >> 9;
    unsigned int d[4] = {0u, 0u, 0u, 0u};
    if (a < 7) {
        const float* row = ker + ((oc * 32 + ic) * 49) + (6 - a) * 7;
        float v[8];
#pragma unroll
        for (int q = 0; q < 7; ++q) v[q] = row[6 - q];
        v[7] = 0.0f;
#pragma unroll
        for (int j = 0; j < 4; ++j)
            d[j] = (unsigned int)f2bf(v[2 * j]) | ((unsigned int)f2bf(v[2 * j + 1]) << 16);
    }
    int ot = oc >> 4, n = oc & 15, kt = a >> 2, g = a & 3;
    B2[(ic * 8 + ot * 2 + kt) * 64 + g * 16 + n] = make_uint4(d[0], d[1], d[2], d[3]);
}

// ---------------------------------------------------------------------------
// Conv: grid 256 = b(8) x rowpair(32); block = 1024 thr (16 waves), computes
// 2 output rows x 64 x x 64 oc over ALL 32 ic. Waves: xh = w&1 (32-px half),
// icg = w>>1 (4-ic group). Per ic a wave loads 8 tap-frags and fires 32 MFMAs
// (4 n-tiles x 4 oc-tiles) -> taps amortized 2x vs R7; img-frag LDS reads
// unchanged. 8 icg-partials merged by an in-LDS tree; plain coalesced stores.
// H (pitch 72, plane stride 576): dword p = pack(bf16 col (p-2)%64, (p-1)%64),
// window row r = img row (y0-2+r)%64, r in [0,8); r==8 (a==7,ry==1) reads the
// next plane / zeroed pad - killed by zero B columns.
// ---------------------------------------------------------------------------
__global__ __launch_bounds__(1024, 4) void conv_mfma(
    const float* __restrict__ img,          // [8][32][64][64]
    const uint4* __restrict__ B2,           // prepped taps
    float* __restrict__ out)                // [8][64][64][64]
{
    __shared__ unsigned int H[18576];       // 32*576 + 144 pad = 74304 B

    const int bid  = blockIdx.x;            // b*32 + yp
    const int yp   = bid & 31;
    const int b    = bid >> 5;
    const int y0   = yp * 2;
    const int tid  = threadIdx.x;
    const int lane = tid & 63;
    const int w    = tid >> 6;              // 16 waves
    const int xh   = w & 1;
    const int icg  = w >> 1;                // 0..7, 4 ic each
    const int n    = lane & 15;
    const int g    = lane >> 4;

    const float* base = img + (size_t)b * 32 * 4096;

    // ---- zero the pad rows (read by plane-31 a==7) ----
    if (tid < 144) H[18432 + tid] = 0u;

    // ---- stage: wave w owns planes 2w, 2w+1, 8 rows each; col = lane ----
    float v[16];
#pragma unroll
    for (int j = 0; j < 16; ++j) {
        const int pl  = 2 * w + (j >> 3);
        const int row = (y0 - 2 + (j & 7)) & 63;
        v[j] = base[pl * 4096 + row * 64 + lane];
    }
#pragma unroll
    for (int j = 0; j < 16; ++j) {
        const int pl = 2 * w + (j >> 3);
        const int r  = j & 7;
        const unsigned int h  = f2bf(v[j]);
        const unsigned int hn = (unsigned int)__shfl((int)h, (lane + 1) & 63);
        const unsigned int dw = h | (hn << 16);   // cols (lane, lane+1) -> dword lane+2
        const int idx = pl * 576 + r * 72;
        H[idx + lane + 2] = dw;
        if (lane >= 62) H[idx + lane - 62] = dw;  // wrap left  (p = 0,1)
        if (lane <= 5)  H[idx + lane + 66] = dw;  // wrap right (p = 66..71)
    }
    __syncthreads();

    // ---- compute: 4 ic x 4 n-tiles x 4 oc-tiles ----
    f32x4 acc[4][4];
#pragma unroll
    for (int nt = 0; nt < 4; ++nt)
#pragma unroll
        for (int ot = 0; ot < 4; ++ot) acc[nt][ot] = (f32x4){0.f, 0.f, 0.f, 0.f};

#pragma unroll 1
    for (int ici = 0; ici < 4; ++ici) {
        const int ic = icg * 4 + ici;
        uint4 bf[8];                              // q = ot*2 + kt
#pragma unroll
        for (int q = 0; q < 8; ++q)
            bf[q] = B2[(ic * 8 + q) * 64 + lane];

#pragma unroll
        for (int nt = 0; nt < 4; ++nt) {          // ry = nt>>1, mt = nt&1
            const int b0 = ic * 576 + ((nt >> 1) + g) * 72 + 32 * xh + 16 * (nt & 1) + n;
            const int b1 = b0 + 288;              // tap row a = g+4
            uint4 i0 = make_uint4(H[b0], H[b0 + 2], H[b0 + 4], H[b0 + 6]);
            uint4 i1 = make_uint4(H[b1], H[b1 + 2], H[b1 + 4], H[b1 + 6]);
            short8 f0 = __builtin_bit_cast(short8, i0);
            short8 f1 = __builtin_bit_cast(short8, i1);
#pragma unroll
            for (int ot = 0; ot < 4; ++ot) {
                f32x4 d = (f32x4){0.f, 0.f, 0.f, 0.f};
                d = __builtin_amdgcn_mfma_f32_16x16x32_bf16(
                        __builtin_bit_cast(short8, bf[2 * ot]),     f0, d, 0, 0, 0);
                d = __builtin_amdgcn_mfma_f32_16x16x32_bf16(
                        __builtin_bit_cast(short8, bf[2 * ot + 1]), f1, d, 0, 0, 0);
#pragma unroll
                for (int i = 0; i < 4; ++i)
                    acc[nt][ot][i] += __builtin_fabsf(d[i]);
            }
        }
    }

    // ---- 8-way icg merge via LDS tree (aliases dead H); conflict-free ----
    float* P = (float*)H;
    __syncthreads();                              // compute done reading H

    // Round A (distance 4), sub-phased by nt-half to fit LDS.
#pragma unroll
    for (int ph = 0; ph < 2; ++ph) {
        if (icg >= 4) {                           // publish nt in {2ph, 2ph+1}
            const int rb = ((icg - 4) * 2 + xh) * 2048;
#pragma unroll
            for (int nh = 0; nh < 2; ++nh) {
                const int nt = 2 * ph + nh;
                float* q = P + rb + (nh * 4 + 0) * 256 + lane * 4;
#pragma unroll
                for (int ot = 0; ot < 4; ++ot)
#pragma unroll
                    for (int i = 0; i < 4; ++i)
                        P[rb + (nh * 4 + ot) * 256 + lane * 4 + i] = acc[nt][ot][i];
                (void)q;
            }
        }
        __syncthreads();
        if (icg < 4) {                            // absorb
            const int rb = (icg * 2 + xh) * 2048;
#pragma unroll
            for (int nh = 0; nh < 2; ++nh) {
                const int nt = 2 * ph + nh;
#pragma unroll
                for (int ot = 0; ot < 4; ++ot)
#pragma unroll
                    for (int i = 0; i < 4; ++i)
                        acc[nt][ot][i] += P[rb + (nh * 4 + ot) * 256 + lane * 4 + i];
            }
        }
        __syncthreads();
    }
    // Round B (distance 2): icg 2,3 publish full acc.
    if (icg == 2 || icg == 3) {
        const int rb = ((icg - 2) * 2 + xh) * 4096;
#pragma unroll
        for (int nt = 0; nt < 4; ++nt)
#pragma unroll
            for (int ot = 0; ot < 4; ++ot)
#pragma unroll
                for (int i = 0; i < 4; ++i)
                    P[rb + (nt * 4 + ot) * 256 + lane * 4 + i] = acc[nt][ot][i];
    }
    __syncthreads();
    if (icg == 0 || icg == 1) {
        const int rb = (icg * 2 + xh) * 4096;
#pragma unroll
        for (int nt = 0; nt < 4; ++nt)
#pragma unroll
            for (int ot = 0; ot < 4; ++ot)
#pragma unroll
                for (int i = 0; i < 4; ++i)
                    acc[nt][ot][i] += P[rb + (nt * 4 + ot) * 256 + lane * 4 + i];
    }
    __syncthreads();
    // Round C (distance 1): icg 1 publishes.
    if (icg == 1) {
        const int rb = xh * 4096;
#pragma unroll
        for (int nt = 0; nt < 4; ++nt)
#pragma unroll
            for (int ot = 0; ot < 4; ++ot)
#pragma unroll
                for (int i = 0; i < 4; ++i)
                    P[rb + (nt * 4 + ot) * 256 + lane * 4 + i] = acc[nt][ot][i];
    }
    __syncthreads();
    if (icg == 0) {                               // final absorb + store
        const int rb = xh * 4096;
        float* o = out + (size_t)b * 64 * 4096;
#pragma unroll
        for (int nt = 0; nt < 4; ++nt) {
            const int y  = y0 + (nt >> 1);
            const int x0 = 32 * xh + 16 * (nt & 1);
#pragma unroll
            for (int ot = 0; ot < 4; ++ot)
#pragma unroll
                for (int i = 0; i < 4; ++i) {
                    const int oc = 16 * ot + 4 * g + i;
                    o[(size_t)oc * 4096 + y * 64 + x0 + n] =
                        acc[nt][ot][i] + P[rb + (nt * 4 + ot) * 256 + lane * 4 + i];
                }
        }
    }
}

} // namespace

extern "C" void kernel_launch(void* const* d_in, const int* in_sizes, int n_in,
                              void* d_out, int out_size, void* d_ws, size_t ws_size,
                              hipStream_t stream) {
    const float* img = (const float*)d_in[0];   // [8][32][64][64]
    const float* ker = (const float*)d_in[1];   // [64][32][7][7]
    float* out = (float*)d_out;                 // [8][64][64][64]
    uint4* B2 = (uint4*)d_ws;                   // 256 KB lane-major taps

    prep_B<<<dim3(64), dim3(256), 0, stream>>>(ker, B2);
    conv_mfma<<<dim3(256), dim3(1024), 0, stream>>>(img, B2, out);
}